// Round 2
// baseline (22447.867 us; speedup 1.0000x reference)
//
#include <hip/hip_runtime.h>
#include <hip/hip_bf16.h>
#include <math.h>

// RSWABlock: x:(16,192,128,128) fp32 -> pre1(1x1) -> dw3x3 -> LN(ch) ->
// 8x8 windows -> (attention * gMLP) -> merge -> proj(1x1) -> + x
// Round 2: fp32 I/O (reference dtype), bf16 staging for p/a in ws,
// h1 staged fp32 inside d_out (dead before k_proj overwrites it).

#define DIM    192
#define IMG_H  128
#define IMG_W  128
#define HW     16384        // 128*128
#define NB     16           // batch
#define NWIN   4096         // 16 batches * 16 * 16 windows
#define NHEADS 6
#define HDIM   32
#define ATT_SCALE 0.17677669529663687f  // 32^-0.5
#define LN_EPS 1e-6f

typedef __hip_bfloat16 bf16;
__device__ __forceinline__ float b2f(bf16 v) { return __bfloat162float(v); }
__device__ __forceinline__ bf16  f2b(float v) { return __float2bfloat16(v); }

// ---------------------------------------------------------------------------
// K1: h1[b,o,hw] = sum_c x[b,c,hw] * w_pre1[o,c] + b_pre1[o]   (all fp32)
// grid (1024, 3): blockIdx.x = 256-pixel tile, blockIdx.y = 64-o tile
// ---------------------------------------------------------------------------
__global__ __launch_bounds__(256) void k_pre1(
    const float* __restrict__ x, const float* __restrict__ w,
    const float* __restrict__ bias, float* __restrict__ h1)
{
    __shared__ __align__(16) float lw[64 * 192];   // 48 KB [o][c]
    const int tid = threadIdx.x;
    const int obase = blockIdx.y * 64;
    for (int i = tid; i < 64 * 192; i += 256)
        lw[i] = w[obase * 192 + i];
    __syncthreads();

    const int g  = blockIdx.x * 256 + tid;      // global pixel in [0, NB*HW)
    const int b  = g >> 14;
    const int hw = g & (HW - 1);
    const float* xb = x + (size_t)b * DIM * HW + hw;

    float acc[64];
#pragma unroll
    for (int o = 0; o < 64; ++o) acc[o] = bias[obase + o];

    for (int c = 0; c < DIM; c += 4) {
        float xv0 = xb[(size_t)(c + 0) * HW];
        float xv1 = xb[(size_t)(c + 1) * HW];
        float xv2 = xb[(size_t)(c + 2) * HW];
        float xv3 = xb[(size_t)(c + 3) * HW];
#pragma unroll
        for (int o = 0; o < 64; ++o) {
            const float4 wv = *(const float4*)&lw[o * 192 + c];
            acc[o] += wv.x * xv0 + wv.y * xv1 + wv.z * xv2 + wv.w * xv3;
        }
    }
    float* hb = h1 + (size_t)b * DIM * HW + hw;
#pragma unroll
    for (int o = 0; o < 64; ++o) hb[(size_t)(obase + o) * HW] = acc[o];
}

// ---------------------------------------------------------------------------
// K2: depthwise 3x3 (SAME) + bias, LayerNorm over channels, window partition.
// One block per window. Writes p[win, t, c] bf16.
// ---------------------------------------------------------------------------
__global__ __launch_bounds__(256) void k_dwln(
    const float* __restrict__ h1, const float* __restrict__ w_dw,
    const float* __restrict__ b_dw, const float* __restrict__ ln_g,
    const float* __restrict__ ln_b, bf16* __restrict__ p)
{
    __shared__ float tile[64 * 192];      // [pix][ch] post-conv, 48 KB
    __shared__ float patch[32 * 101];     // [ch][10x10 + pad], 12.9 KB
    const int tid = threadIdx.x;
    const int win = blockIdx.x;
    const int b = win >> 8, rem = win & 255;
    const int r0 = (rem >> 4) * 8, c0 = (rem & 15) * 8;

    for (int cc = 0; cc < 6; ++cc) {      // 6 chunks of 32 channels
        for (int i = tid; i < 3200; i += 256) {
            int ch = i / 100, pp = i % 100;
            int pr = pp / 10, pc = pp % 10;
            int gy = r0 - 1 + pr, gx = c0 - 1 + pc;
            float v = 0.f;
            if ((unsigned)gy < 128u && (unsigned)gx < 128u)
                v = h1[(((size_t)b * DIM + cc * 32 + ch) * IMG_H + gy) * IMG_W + gx];
            patch[ch * 101 + pp] = v;
        }
        __syncthreads();
        for (int i = tid; i < 2048; i += 256) {     // 64 pix * 32 ch
            int pix = i >> 5, chl = i & 31;
            int ch = cc * 32 + chl;
            int r = pix >> 3, c = pix & 7;
            float acc = b_dw[ch];
#pragma unroll
            for (int ky = 0; ky < 3; ++ky)
#pragma unroll
                for (int kx = 0; kx < 3; ++kx)
                    acc = fmaf(w_dw[ch * 9 + ky * 3 + kx],
                               patch[chl * 101 + (r + ky) * 10 + (c + kx)], acc);
            tile[pix * 192 + ch] = acc;
        }
        __syncthreads();
    }
    // LayerNorm per pixel over 192 channels: 4 threads per pixel
    const int pix = tid >> 2, sub = tid & 3;
    float s1 = 0.f, s2 = 0.f;
    for (int j = 0; j < 48; ++j) {
        float v = tile[pix * 192 + sub * 48 + j];
        s1 += v; s2 += v * v;
    }
    s1 += __shfl_xor(s1, 1); s2 += __shfl_xor(s2, 1);
    s1 += __shfl_xor(s1, 2); s2 += __shfl_xor(s2, 2);
    float mu  = s1 * (1.f / 192.f);
    float var = fmaxf(s2 * (1.f / 192.f) - mu * mu, 0.f);
    float rstd = rsqrtf(var + LN_EPS);
    bf16* pout = p + ((size_t)win * 64 + pix) * 192 + sub * 48;
    for (int j = 0; j < 48; ++j) {
        int c = sub * 48 + j;
        pout[j] = f2b((tile[pix * 192 + c] - mu) * rstd * ln_g[c] + ln_b[c]);
    }
}

// ---------------------------------------------------------------------------
// K3: per-window QKV + softmax attention. One block per window, loop heads.
// ---------------------------------------------------------------------------
__global__ __launch_bounds__(256) void k_attn(
    const bf16* __restrict__ p, const float* __restrict__ w_qkv,
    const float* __restrict__ b_qkv, bf16* __restrict__ a)
{
    __shared__ float qs[64 * 33], ks[64 * 33], vs[64 * 33];  // padded
    __shared__ float ss[64 * 65];                            // scores
    const int tid = threadIdx.x;
    const int win = blockIdx.x;
    const bf16* pwin = p + (size_t)win * 64 * 192;

    for (int h = 0; h < NHEADS; ++h) {
        for (int i = tid; i < 2048; i += 256) {
            int t = i >> 5, j = i & 31;
            int e = h * 32 + j;
            float aq = b_qkv[e];
            float ak = b_qkv[192 + e];
            float av = b_qkv[384 + e];
            const bf16* pr = pwin + t * 192;
            const float* wq = w_qkv + e;
            for (int c = 0; c < 192; ++c) {
                float pv = b2f(pr[c]);
                aq = fmaf(pv, wq[c * 576], aq);
                ak = fmaf(pv, wq[c * 576 + 192], ak);
                av = fmaf(pv, wq[c * 576 + 384], av);
            }
            qs[t * 33 + j] = aq * ATT_SCALE;   // fold scale into q
            ks[t * 33 + j] = ak;
            vs[t * 33 + j] = av;
        }
        __syncthreads();
        for (int i = tid; i < 4096; i += 256) {          // S = q k^T
            int t = i >> 6, u = i & 63;
            float acc = 0.f;
#pragma unroll
            for (int j = 0; j < 32; ++j) acc = fmaf(qs[t * 33 + j], ks[u * 33 + j], acc);
            ss[t * 65 + u] = acc;
        }
        __syncthreads();
        {   // softmax rows: 4 threads / row
            const int t = tid >> 2, sub = tid & 3;
            float m = -1e30f;
            for (int j = 0; j < 16; ++j) m = fmaxf(m, ss[t * 65 + sub * 16 + j]);
            m = fmaxf(m, __shfl_xor(m, 1));
            m = fmaxf(m, __shfl_xor(m, 2));
            float sum = 0.f;
            for (int j = 0; j < 16; ++j) {
                float e = __expf(ss[t * 65 + sub * 16 + j] - m);
                ss[t * 65 + sub * 16 + j] = e;
                sum += e;
            }
            sum += __shfl_xor(sum, 1);
            sum += __shfl_xor(sum, 2);
            float inv = 1.f / sum;
            for (int j = 0; j < 16; ++j) ss[t * 65 + sub * 16 + j] *= inv;
        }
        __syncthreads();
        for (int i = tid; i < 2048; i += 256) {          // O = P v
            int t = i >> 5, j = i & 31;
            float acc = 0.f;
#pragma unroll
            for (int u = 0; u < 64; ++u) acc = fmaf(ss[t * 65 + u], vs[u * 33 + j], acc);
            a[((size_t)win * 64 + t) * 192 + h * 32 + j] = f2b(acc);
        }
        __syncthreads();
    }
}

// ---------------------------------------------------------------------------
// K4: gMLP (gelu(p@w1+b1)@w2+b2), multiply with attention output in-place.
// One block per half-window (32 tokens). grid 8192.
// ---------------------------------------------------------------------------
__global__ __launch_bounds__(256) void k_gmlp(
    const bf16* __restrict__ p, const float* __restrict__ w1,
    const float* __restrict__ b1, const float* __restrict__ w2,
    const float* __restrict__ b2, bf16* __restrict__ a)
{
    __shared__ float pw[32 * 192];    // tokens
    __shared__ float hid[32 * 193];   // gelu(hidden chunk), padded
    const int tid = threadIdx.x;
    const int win = blockIdx.x >> 1;
    const int thalf = (blockIdx.x & 1) * 32;
    const bf16* pwin = p + ((size_t)win * 64 + thalf) * 192;
    for (int i = tid; i < 6144; i += 256) pw[i] = b2f(pwin[i]);

    const int lt = tid >> 3, obase = (tid & 7) * 24;
    float acc[24];
#pragma unroll
    for (int oo = 0; oo < 24; ++oo) acc[oo] = b2[obase + oo];
    __syncthreads();

    for (int hc = 0; hc < 4; ++hc) {   // hidden 768 in 4 chunks of 192
        for (int i = tid; i < 6144; i += 256) {
            int tt = i / 192, j = i % 192;
            int hj = hc * 192 + j;
            float s = b1[hj];
            const float* w1c = w1 + hj;
            for (int c = 0; c < 192; ++c)
                s = fmaf(pw[tt * 192 + c], w1c[(size_t)c * 768], s);
            hid[tt * 193 + j] = 0.5f * s * (1.f + erff(s * 0.70710678118654752f));
        }
        __syncthreads();
        for (int j = 0; j < 192; ++j) {
            float hv = hid[lt * 193 + j];
            const float* w2r = w2 + ((size_t)hc * 192 + j) * 192 + obase;
#pragma unroll
            for (int oo = 0; oo < 24; ++oo)
                acc[oo] = fmaf(hv, w2r[oo], acc[oo]);
        }
        __syncthreads();
    }
    bf16* arow = a + ((size_t)win * 64 + thalf + lt) * 192 + obase;
#pragma unroll
    for (int oo = 0; oo < 24; ++oo)
        arow[oo] = f2b(acc[oo] * b2f(arow[oo]));   // attn * gmlp, in-place
}

// ---------------------------------------------------------------------------
// K5: proj 1x1 + bias + residual, store NCHW fp32 to d_out.
// One block per half-window (32 tokens). grid 8192.
// ---------------------------------------------------------------------------
__global__ __launch_bounds__(256) void k_proj(
    const bf16* __restrict__ m, const float* __restrict__ w_proj,
    const float* __restrict__ b_proj, const float* __restrict__ x,
    float* __restrict__ out)
{
    __shared__ float mw[32 * 194];    // tokens, padded
    __shared__ float ot[32 * 193];    // [pix][o] result, padded
    const int tid = threadIdx.x;
    const int win = blockIdx.x >> 1;
    const int thalf = (blockIdx.x & 1) * 32;
    const int b = win >> 8, rem = win & 255;
    const int r0 = (rem >> 4) * 8, c0 = (rem & 15) * 8;
    const bf16* mwin = m + ((size_t)win * 64 + thalf) * 192;
    for (int i = tid; i < 6144; i += 256) {
        int tt = i / 192, c = i % 192;
        mw[tt * 194 + c] = b2f(mwin[i]);
    }
    const int lt = tid >> 3, obase = (tid & 7) * 24;
    float acc[24];
#pragma unroll
    for (int oo = 0; oo < 24; ++oo) acc[oo] = b_proj[obase + oo];
    __syncthreads();

    for (int c = 0; c < 192; ++c) {
        float mv = mw[lt * 194 + c];
#pragma unroll
        for (int oo = 0; oo < 24; ++oo)
            acc[oo] = fmaf(mv, w_proj[(size_t)(obase + oo) * 192 + c], acc[oo]);
    }
#pragma unroll
    for (int oo = 0; oo < 24; ++oo) ot[lt * 193 + obase + oo] = acc[oo];
    __syncthreads();

    for (int i = tid; i < 6144; i += 256) {
        int o = i >> 5, pix = i & 31;       // 192 o x 32 pix
        int t = thalf + pix;
        size_t idx = (((size_t)b * DIM + o) * IMG_H + r0 + (t >> 3)) * IMG_W
                     + c0 + (t & 7);
        out[idx] = ot[pix * 193 + o] + x[idx];   // + residual
    }
}

// ---------------------------------------------------------------------------
extern "C" void kernel_launch(void* const* d_in, const int* in_sizes, int n_in,
                              void* d_out, int out_size, void* d_ws, size_t ws_size,
                              hipStream_t stream)
{
    const float* x      = (const float*)d_in[0];
    const float* w_pre1 = (const float*)d_in[1];
    const float* b_pre1 = (const float*)d_in[2];
    const float* w_dw   = (const float*)d_in[3];
    const float* b_dw   = (const float*)d_in[4];
    const float* ln_g   = (const float*)d_in[5];
    const float* ln_b   = (const float*)d_in[6];
    const float* w_qkv  = (const float*)d_in[7];
    const float* b_qkv  = (const float*)d_in[8];
    const float* w1     = (const float*)d_in[9];
    const float* b1     = (const float*)d_in[10];
    const float* w2     = (const float*)d_in[11];
    const float* b2     = (const float*)d_in[12];
    const float* w_proj = (const float*)d_in[13];
    const float* b_proj = (const float*)d_in[14];
    float* out = (float*)d_out;

    const size_t NELEM = (size_t)NB * DIM * HW;   // 50,331,648
    // h1 lives fp32 inside d_out (dead before k_proj overwrites d_out)
    float* h1 = (float*)d_out;
    bf16* p = (bf16*)d_ws;           // LN'd window tokens (win, t, c)
    bf16* a = p + NELEM;             // attn out, then attn*gmlp (in-place)

    k_pre1<<<dim3(1024, 3), 256, 0, stream>>>(x, w_pre1, b_pre1, h1);
    k_dwln<<<dim3(NWIN), 256, 0, stream>>>(h1, w_dw, b_dw, ln_g, ln_b, p);
    k_attn<<<dim3(NWIN), 256, 0, stream>>>(p, w_qkv, b_qkv, a);
    k_gmlp<<<dim3(NWIN * 2), 256, 0, stream>>>(p, w1, b1, w2, b2, a);
    k_proj<<<dim3(NWIN * 2), 256, 0, stream>>>(a, w_proj, b_proj, x, out);
}